// Round 5
// baseline (160.469 us; speedup 1.0000x reference)
//
#include <hip/hip_runtime.h>
#include <hip/hip_cooperative_groups.h>
#include <math.h>

namespace cg = cooperative_groups;

#define NN 1024
#define CC 91
#define MAXDET 100
typedef unsigned long long ull;
#define SENT 0xFFFFFFFFFFFFFFFFULL

struct alignas(16) D4 { double x, y, z, w; };

// One cooperative kernel, 256 blocks x 1024 threads (1 block/CU co-resident).
// Phase 1: wave-per-pid softmax (4 pids/wave) + lane 0-3 decode  -> global ws
// Phase 2: 1440 (image,class) NMS waves spread across all blocks -> keptKey
// Phase 3: blocks 0..15 per-image bitonic top-100                -> out
__global__ __launch_bounds__(1024, 4) void fused_all(
    const float* __restrict__ logits, const float* __restrict__ deltas,
    const float* __restrict__ props,  const int* __restrict__ imsz,
    D4* __restrict__ dbox, double* __restrict__ score64,
    int* __restrict__ label, ull* __restrict__ skeyG, ull* __restrict__ keptKey,
    float* __restrict__ out)
{
    __shared__ int sMemb[16 * 64];
    __shared__ int sPosR[16 * 64];
    __shared__ ull sKeyR[16 * 64];
    __shared__ ull sRun[NN];

    cg::grid_group grid = cg::this_grid();
    int t = threadIdx.x, lane = t & 63, wv = t >> 6;

    // ---------------- Phase 1: softmax + decode (4 pids per wave) ------------
    {
        int gwave = blockIdx.x * 16 + wv;        // 0..4095
        double e_my = 1.0; int idx_my = 0;       // set at q==lane for lanes 0..3
        #pragma unroll
        for (int q = 0; q < 4; ++q) {
            int pid = gwave * 4 + q;
            const float* lg = logits + (size_t)pid * CC;
            float v0 = lg[lane];
            float v1 = (lane < CC - 64) ? lg[64 + lane] : -INFINITY;
            float m; int idx;
            if (v0 >= v1) { m = v0; idx = lane; } else { m = v1; idx = 64 + lane; }
            #pragma unroll
            for (int off = 32; off > 0; off >>= 1) {
                float om = __shfl_xor(m, off);
                int   oi = __shfl_xor(idx, off);
                if (om > m || (om == m && oi < idx)) { m = om; idx = oi; }
            }
            // exp(-inf - m) == 0.0 exactly, so unconditional add is bit-identical
            double e = exp((double)v0 - (double)m) + exp((double)v1 - (double)m);
            #pragma unroll
            for (int off = 32; off > 0; off >>= 1) e += __shfl_xor(e, off);
            if (lane == q) { e_my = e; idx_my = idx; }   // q is compile-time
        }
        if (lane < 4) {                           // 4 parallel decodes per wave
            int pid = gwave * 4 + lane;
            double score = 1.0 / e_my;
            int lbl = idx_my;
            int vld = (lbl > 0 && score > 0.05) ? 1 : 0;
            float4 d = ((const float4*)deltas)[(size_t)pid * CC + lbl];
            float4 p = ((const float4*)props)[pid];
            double w  = (double)p.z - (double)p.x;
            double h  = (double)p.w - (double)p.y;
            double cx = (double)p.x + 0.5 * w;
            double cy = (double)p.y + 0.5 * h;
            const double CLIPV = 4.135166556742356;  // log(1000/16) in f64
            double dw = fmin((double)d.z, CLIPV), dh = fmin((double)d.w, CLIPV);
            double pcx = (double)d.x * w + cx, pcy = (double)d.y * h + cy;
            double pw = exp(dw) * w, ph = exp(dh) * h;
            double x1 = pcx - 0.5 * pw, y1 = pcy - 0.5 * ph;
            double x2 = pcx + 0.5 * pw, y2 = pcy + 0.5 * ph;
            int b = pid >> 10;
            double bw = (double)imsz[b * 2 + 1], bh = (double)imsz[b * 2 + 0];
            x1 = fmin(fmax(x1, 0.0), bw); y1 = fmin(fmax(y1, 0.0), bh);
            x2 = fmin(fmax(x2, 0.0), bw); y2 = fmin(fmax(y2, 0.0), bh);
            dbox[pid]    = D4{x1, y1, x2, y2};
            score64[pid] = score;
            label[pid]   = vld ? lbl : 0;        // 0 = skip in per-class NMS
            double seff = vld ? score : -1e300;
            ull u   = (ull)__double_as_longlong(seff);
            ull asc = (u >> 63) ? ~u : (u | 0x8000000000000000ULL);
            skeyG[pid]   = (~asc & ~1023ULL) | (ull)(pid & 1023);
            keptKey[pid] = SENT;
        }
    }
    grid.sync();

    // ---------------- Phase 2: greedy per-class NMS --------------------------
    {
        int gw = blockIdx.x + 256 * wv;          // spread over all blocks/CUs
        if (gw < 1440) {
            int b  = gw / 90;
            int c  = 1 + gw % 90;                // classes 1..90
            int base = b * NN;
            ull lmlt = (lane == 0) ? 0ULL : ((1ULL << lane) - 1ULL);

            int myl[16];                         // hoisted independent loads
            #pragma unroll
            for (int w = 0; w < 16; ++w) myl[w] = label[base + w * 64 + lane];

            int nmem = 0;
            #pragma unroll
            for (int w = 0; w < 16; ++w) {
                bool match = (myl[w] == c);
                ull mb = __ballot(match);
                if (match) {
                    int slot = nmem + (int)__popcll(mb & lmlt);
                    if (slot < 64) sMemb[wv * 64 + slot] = w * 64 + lane;
                }
                nmem += (int)__popcll(mb);
                if (nmem >= 64) break;           // wave-uniform
            }
            int n = nmem < 64 ? nmem : 64;
            if (n > 0) {
                int p = sMemb[wv * 64 + (lane < n ? lane : 0)];
                ull key = skeyG[base + p];
                int rank = 0;
                for (int j = 0; j < n; ++j) {
                    ull kj = __shfl(key, j);
                    rank += (int)(kj < key);
                }
                if (lane < n) { sPosR[wv * 64 + rank] = p; sKeyR[wv * 64 + rank] = key; }
                int rl  = wv * 64 + (lane < n ? lane : 0);
                int p2  = sPosR[rl];
                ull k2v = sKeyR[rl];

                D4 bx = dbox[base + p2];         // lane r holds rank-r box
                double ma = (bx.z - bx.x) * (bx.w - bx.y);
                ull pm = 0;
                for (int j = 0; j < n; ++j) {
                    double jx = __shfl(bx.x, j), jy = __shfl(bx.y, j);
                    double jz = __shfl(bx.z, j), jw = __shfl(bx.w, j);
                    double ja = __shfl(ma, j);
                    double xx1 = fmax(bx.x, jx), yy1 = fmax(bx.y, jy);
                    double xx2 = fmin(bx.z, jz), yy2 = fmin(bx.w, jw);
                    double iw = fmax(xx2 - xx1, 0.0), ih = fmax(yy2 - yy1, 0.0);
                    double inter = iw * ih;
                    bool hit = (inter > 0.5 * (ma + ja - inter + 1e-9)) && (j < lane);
                    pm |= ((ull)hit) << j;
                }
                bool act = lane < n;
                ull avail = __ballot(act);
                ull keptw = 0; bool supp = false;
                while (avail) {
                    int k0 = __builtin_ctzll(avail);
                    keptw |= 1ULL << k0;
                    supp = supp || ((pm >> k0) & 1ULL);
                    avail &= ~__ballot(supp);
                    avail &= ~((2ULL << k0) - 1ULL);   // k0=63 -> 0
                }
                if (act && ((keptw >> lane) & 1ULL)) keptKey[base + p2] = k2v;
            }
        }
    }
    grid.sync();

    // ---------------- Phase 3: per-image top-100 (blocks 0..15) --------------
    if (blockIdx.x < 16) {
        int b = blockIdx.x;
        int base = b * NN;

        ull key = keptKey[base + t];
        for (int k = 2; k <= 64; k <<= 1)
            for (int j = k >> 1; j > 0; j >>= 1) {
                ull part = __shfl_xor(key, j);
                bool keepMin = ((lane & j) == 0) == ((lane & k) == 0);
                ull mn = key < part ? key : part;
                ull mx = key < part ? part : key;
                key = keepMin ? mn : mx;
            }
        sRun[wv * 64 + lane] = key;
        __syncthreads();

        if (wv < 8) {
            ull a  = sRun[wv * 128 + lane];
            ull bb = sRun[wv * 128 + 64 + lane];
            ull br = __shfl(bb, 63 - lane);
            ull lo = a < br ? a : br;
            ull hi = a < br ? br : a;
            #pragma unroll
            for (int j = 32; j > 0; j >>= 1) {
                bool km = ((lane & j) == 0);
                ull pl = __shfl_xor(lo, j);
                lo = km ? (lo < pl ? lo : pl) : (lo < pl ? pl : lo);
                ull ph = __shfl_xor(hi, j);
                hi = km ? (hi < ph ? hi : ph) : (hi < ph ? ph : hi);
            }
            sRun[wv * 128 + lane] = lo;
            sRun[wv * 128 + 64 + lane] = hi;
        }
        for (int nm = 4; nm >= 1; nm >>= 1) {
            __syncthreads();
            ull Alo = 0, Ahi = 0, Blo = 0, Bhi = 0;
            if (wv < nm) {
                Alo = sRun[wv * 256 + lane];
                Ahi = sRun[wv * 256 + 64 + lane];
                Blo = sRun[wv * 256 + 128 + lane];
                Bhi = sRun[wv * 256 + 192 + lane];
            }
            __syncthreads();
            if (wv < nm) {
                ull rBhi = __shfl(Bhi, 63 - lane);
                ull rBlo = __shfl(Blo, 63 - lane);
                ull Mlo = Alo < rBhi ? Alo : rBhi;
                ull Mhi = Ahi < rBlo ? Ahi : rBlo;
                ull l2 = Mlo < Mhi ? Mlo : Mhi;
                ull h2 = Mlo < Mhi ? Mhi : Mlo;
                #pragma unroll
                for (int j = 32; j > 0; j >>= 1) {
                    bool km = ((lane & j) == 0);
                    ull pl = __shfl_xor(l2, j);
                    l2 = km ? (l2 < pl ? l2 : pl) : (l2 < pl ? pl : l2);
                    ull ph = __shfl_xor(h2, j);
                    h2 = km ? (h2 < ph ? h2 : ph) : (h2 < ph ? ph : h2);
                }
                sRun[wv * 128 + lane] = l2;
                sRun[wv * 128 + 64 + lane] = h2;
            }
        }
        if (wv == 0) {
            float* oBox   = out;
            float* oScore = out + 6400;
            float* oLabel = out + 8000;
            #pragma unroll
            for (int rsel = 0; rsel < 2; ++rsel) {
                int rank = rsel * 64 + lane;
                if (rank < MAXDET) {
                    ull kf = sRun[rsel * 64 + lane];
                    int q = b * MAXDET + rank;
                    if (kf == SENT) {
                        oBox[q * 4 + 0] = 0.f; oBox[q * 4 + 1] = 0.f;
                        oBox[q * 4 + 2] = 0.f; oBox[q * 4 + 3] = 0.f;
                        oScore[q] = 0.f;
                        oLabel[q] = -1.f;
                    } else {
                        int p = (int)(kf & 1023ULL);
                        D4 bx = dbox[base + p];
                        oBox[q * 4 + 0] = (float)bx.x; oBox[q * 4 + 1] = (float)bx.y;
                        oBox[q * 4 + 2] = (float)bx.z; oBox[q * 4 + 3] = (float)bx.w;
                        oScore[q] = (float)score64[base + p];
                        oLabel[q] = (float)label[base + p];
                    }
                }
            }
        }
    }
}

// ---------------- launch ------------------------------------------------------
extern "C" void kernel_launch(void* const* d_in, const int* in_sizes, int n_in,
                              void* d_out, int out_size, void* d_ws, size_t ws_size,
                              hipStream_t stream) {
    const float* logits = (const float*)d_in[0];
    const float* deltas = (const float*)d_in[1];
    const float* props  = (const float*)d_in[2];
    const int*   imsz   = (const int*)d_in[3];
    char* ws = (char*)d_ws;
    D4*     dbox    = (D4*)(ws + 0);              // 524288
    double* score64 = (double*)(ws + 524288);     // 131072
    int*    label   = (int*)(ws + 655360);        // 65536
    ull*    skeyG   = (ull*)(ws + 720896);        // 131072
    ull*    keptKey = (ull*)(ws + 851968);        // 131072
    float*  out     = (float*)d_out;

    void* args[] = { (void*)&logits, (void*)&deltas, (void*)&props, (void*)&imsz,
                     (void*)&dbox, (void*)&score64, (void*)&label, (void*)&skeyG,
                     (void*)&keptKey, (void*)&out };
    hipLaunchCooperativeKernel((const void*)fused_all, dim3(256), dim3(1024),
                               args, 0, stream);
}

// Round 8
// 95.977 us; speedup vs baseline: 1.6720x; 1.6720x over previous
//
#include <hip/hip_runtime.h>
#include <math.h>

#define NN 1024
#define CC 91
#define MAXDET 100
typedef unsigned long long ull;
#define SENT 0xFFFFFFFFFFFFFFFFULL

struct alignas(16) D4 { double x, y, z, w; };

// ---------------- K1: wave-per-pid softmax + block-level parallel decode ------
// Softmax identical to verified k1a (1 pid/wave, 16384 waves). The decode tail
// (verified k1b body) runs on threads 0..3 of each block via a 32B LDS handoff
// instead of a global sumE/argI round-trip + separate launch.
__global__ __launch_bounds__(256) void k1_fused(
    const float* __restrict__ logits, const float* __restrict__ deltas,
    const float* __restrict__ props,  const int* __restrict__ imsz,
    D4* __restrict__ dbox, double* __restrict__ score64,
    int* __restrict__ label, ull* __restrict__ skeyG, ull* __restrict__ keptKey)
{
    __shared__ double sE[4];
    __shared__ int    sI[4];
    int lane = threadIdx.x & 63;
    int wv   = threadIdx.x >> 6;
    int pid  = blockIdx.x * 4 + wv;            // 0..16383
    const float* lg = logits + (size_t)pid * CC;

    float v0 = lg[lane];
    float v1 = (lane < CC - 64) ? lg[64 + lane] : -INFINITY;
    float m; int idx;
    if (v0 >= v1) { m = v0; idx = lane; } else { m = v1; idx = 64 + lane; }
    #pragma unroll
    for (int off = 32; off > 0; off >>= 1) {
        float om = __shfl_xor(m, off);
        int   oi = __shfl_xor(idx, off);
        if (om > m || (om == m && oi < idx)) { m = om; idx = oi; }
    }
    // exp(-inf - m) == 0.0 exactly -> unconditional add is bit-identical
    double e = exp((double)v0 - (double)m) + exp((double)v1 - (double)m);
    #pragma unroll
    for (int off = 32; off > 0; off >>= 1) e += __shfl_xor(e, off);

    if (lane == 0) { sE[wv] = e; sI[wv] = idx; }
    __syncthreads();

    int t = threadIdx.x;
    if (t < 4) {                               // decode the block's 4 pids
        int pid2 = blockIdx.x * 4 + t;
        double score = 1.0 / sE[t];
        int lbl = sI[t];
        int vld = (lbl > 0 && score > 0.05) ? 1 : 0;
        float4 d = ((const float4*)deltas)[(size_t)pid2 * CC + lbl]; // 16B aligned
        float4 p = ((const float4*)props)[pid2];
        double w  = (double)p.z - (double)p.x;
        double h  = (double)p.w - (double)p.y;
        double cx = (double)p.x + 0.5 * w;
        double cy = (double)p.y + 0.5 * h;
        const double CLIPV = 4.135166556742356;  // log(1000/16) in f64
        double dw = fmin((double)d.z, CLIPV), dh = fmin((double)d.w, CLIPV);
        double pcx = (double)d.x * w + cx, pcy = (double)d.y * h + cy;
        double pw = exp(dw) * w, ph = exp(dh) * h;
        double x1 = pcx - 0.5 * pw, y1 = pcy - 0.5 * ph;
        double x2 = pcx + 0.5 * pw, y2 = pcy + 0.5 * ph;
        int b = pid2 >> 10;
        double bw = (double)imsz[b * 2 + 1], bh = (double)imsz[b * 2 + 0];
        x1 = fmin(fmax(x1, 0.0), bw); y1 = fmin(fmax(y1, 0.0), bh);
        x2 = fmin(fmax(x2, 0.0), bw); y2 = fmin(fmax(y2, 0.0), bh);
        dbox[pid2]    = D4{x1, y1, x2, y2};
        score64[pid2] = score;
        label[pid2]   = vld ? lbl : 0;         // 0 = skip in per-class NMS
        // sort key: descending score, ascending orig idx (stable argsort(-s))
        double seff = vld ? score : -1e300;
        ull u   = (ull)__double_as_longlong(seff);
        ull asc = (u >> 63) ? ~u : (u | 0x8000000000000000ULL);
        skeyG[pid2]   = (~asc & ~1023ULL) | (ull)(pid2 & 1023);
        keptKey[pid2] = SENT;
    }
}

// ---------------- K2: one wave per (image,class) greedy NMS -------------------
__global__ __launch_bounds__(256) void k2_nms(
    const D4* __restrict__ dbox, const int* __restrict__ label,
    const ull* __restrict__ skeyG, ull* __restrict__ keptKey)
{
    __shared__ int sMemb[4 * 64];
    __shared__ int sPosR[4 * 64];
    __shared__ ull sKeyR[4 * 64];
    int lane = threadIdx.x & 63, wv = threadIdx.x >> 6;
    int gw = blockIdx.x * 4 + wv;              // 0..1439
    int b  = gw / 90;
    int c  = 1 + gw % 90;                      // classes 1..90
    int base = b * NN;
    ull lmlt = (lane == 0) ? 0ULL : ((1ULL << lane) - 1ULL);

    // hoist: 16 independent coalesced loads -> one exposed latency
    int myl[16];
    #pragma unroll
    for (int w = 0; w < 16; ++w) myl[w] = label[base + w * 64 + lane];

    // ballot-scan members of class c (position order; n>64 impossible, clamp)
    int nmem = 0;
    #pragma unroll
    for (int w = 0; w < 16; ++w) {
        bool match = (myl[w] == c);
        ull mb = __ballot(match);
        if (match) {
            int slot = nmem + (int)__popcll(mb & lmlt);
            if (slot < 64) sMemb[wv * 64 + slot] = w * 64 + lane;
        }
        nmem += (int)__popcll(mb);
        if (nmem >= 64) break;                 // wave-uniform
    }
    int n = nmem < 64 ? nmem : 64;
    if (n == 0) return;                        // no __syncthreads in this kernel

    // rank members by key (score desc, idx asc)
    int p = sMemb[wv * 64 + (lane < n ? lane : 0)];
    ull key = skeyG[base + p];
    int rank = 0;
    for (int j = 0; j < n; ++j) {
        ull kj = __shfl(key, j);
        rank += (int)(kj < key);
    }
    if (lane < n) { sPosR[wv * 64 + rank] = p; sKeyR[wv * 64 + rank] = key; }
    // same-wave DS ops complete in order; compiler inserts lgkmcnt waits
    int rl  = wv * 64 + (lane < n ? lane : 0);
    int p2  = sPosR[rl];
    ull k2v = sKeyR[rl];

    D4 bx = dbox[base + p2];                   // lane r holds rank-r box
    double ma = (bx.z - bx.x) * (bx.w - bx.y);
    ull pm = 0;                                // predecessor-hit mask (rank space)
    for (int j = 0; j < n; ++j) {
        double jx = __shfl(bx.x, j), jy = __shfl(bx.y, j);
        double jz = __shfl(bx.z, j), jw = __shfl(bx.w, j);
        double ja = __shfl(ma, j);
        double xx1 = fmax(bx.x, jx), yy1 = fmax(bx.y, jy);
        double xx2 = fmin(bx.z, jz), yy2 = fmin(bx.w, jw);
        double iw = fmax(xx2 - xx1, 0.0), ih = fmax(yy2 - yy1, 0.0);
        double inter = iw * ih;
        bool hit = (inter > 0.5 * (ma + ja - inter + 1e-9)) && (j < lane);
        pm |= ((ull)hit) << j;
    }
    bool act = lane < n;
    ull avail = __ballot(act);
    ull keptw = 0; bool supp = false;
    while (avail) {
        int k0 = __builtin_ctzll(avail);
        keptw |= 1ULL << k0;
        supp = supp || ((pm >> k0) & 1ULL);
        avail &= ~__ballot(supp);
        avail &= ~((2ULL << k0) - 1ULL);       // k0=63 -> 0
    }
    if (act && ((keptw >> lane) & 1ULL)) keptKey[base + p2] = k2v;
}

// ---------------- K3: per-image top-100 by key via bitonic partial merges -----
__global__ __launch_bounds__(1024) void k3_top(
    const D4* __restrict__ dbox, const double* __restrict__ score64,
    const int* __restrict__ label, const ull* __restrict__ keptKey,
    float* __restrict__ out)
{
    __shared__ ull sRun[NN];
    int b = blockIdx.x, t = threadIdx.x;
    int lane = t & 63, wv = t >> 6;
    int base = b * NN;

    // in-wave 64-element bitonic sort, ascending (key asc == score desc)
    ull key = keptKey[base + t];
    for (int k = 2; k <= 64; k <<= 1)
        for (int j = k >> 1; j > 0; j >>= 1) {
            ull part = __shfl_xor(key, j);
            bool keepMin = ((lane & j) == 0) == ((lane & k) == 0);
            ull mn = key < part ? key : part;
            ull mx = key < part ? part : key;
            key = keepMin ? mn : mx;
        }
    sRun[wv * 64 + lane] = key;
    __syncthreads();

    // L1: merge pairs of sorted-64 -> sorted-128 (waves 0..7)
    if (wv < 8) {
        ull a  = sRun[wv * 128 + lane];
        ull bb = sRun[wv * 128 + 64 + lane];
        ull br = __shfl(bb, 63 - lane);
        ull lo = a < br ? a : br;
        ull hi = a < br ? br : a;
        #pragma unroll
        for (int j = 32; j > 0; j >>= 1) {
            bool km = ((lane & j) == 0);
            ull pl = __shfl_xor(lo, j);
            lo = km ? (lo < pl ? lo : pl) : (lo < pl ? pl : lo);
            ull ph = __shfl_xor(hi, j);
            hi = km ? (hi < ph ? hi : ph) : (hi < ph ? ph : hi);
        }
        sRun[wv * 128 + lane] = lo;
        sRun[wv * 128 + 64 + lane] = hi;
    }
    // L2..L4: truncated merges of sorted-128 pairs -> smallest-128 sorted
    for (int nm = 4; nm >= 1; nm >>= 1) {
        __syncthreads();
        ull Alo = 0, Ahi = 0, Blo = 0, Bhi = 0;
        if (wv < nm) {
            Alo = sRun[wv * 256 + lane];
            Ahi = sRun[wv * 256 + 64 + lane];
            Blo = sRun[wv * 256 + 128 + lane];
            Bhi = sRun[wv * 256 + 192 + lane];
        }
        __syncthreads();
        if (wv < nm) {
            ull rBhi = __shfl(Bhi, 63 - lane);
            ull rBlo = __shfl(Blo, 63 - lane);
            ull Mlo = Alo < rBhi ? Alo : rBhi;   // min(A[i], B[127-i]) -> bitonic,
            ull Mhi = Ahi < rBlo ? Ahi : rBlo;   // contains the 128 smallest
            ull l2 = Mlo < Mhi ? Mlo : Mhi;      // clean stage j=64
            ull h2 = Mlo < Mhi ? Mhi : Mlo;
            #pragma unroll
            for (int j = 32; j > 0; j >>= 1) {
                bool km = ((lane & j) == 0);
                ull pl = __shfl_xor(l2, j);
                l2 = km ? (l2 < pl ? l2 : pl) : (l2 < pl ? pl : l2);
                ull ph = __shfl_xor(h2, j);
                h2 = km ? (h2 < ph ? h2 : ph) : (h2 < ph ? ph : h2);
            }
            sRun[wv * 128 + lane] = l2;
            sRun[wv * 128 + 64 + lane] = h2;
        }
    }
    // wave 0 wrote final sorted-128 to sRun[0..127]; same-wave read is ordered
    if (wv == 0) {
        float* oBox   = out;
        float* oScore = out + 6400;
        float* oLabel = out + 8000;
        #pragma unroll
        for (int rsel = 0; rsel < 2; ++rsel) {
            int rank = rsel * 64 + lane;
            if (rank < MAXDET) {
                ull kf = sRun[rsel * 64 + lane];
                int q = b * MAXDET + rank;
                if (kf == SENT) {
                    oBox[q * 4 + 0] = 0.f; oBox[q * 4 + 1] = 0.f;
                    oBox[q * 4 + 2] = 0.f; oBox[q * 4 + 3] = 0.f;
                    oScore[q] = 0.f;
                    oLabel[q] = -1.f;
                } else {
                    int p = (int)(kf & 1023ULL);
                    D4 bx = dbox[base + p];
                    oBox[q * 4 + 0] = (float)bx.x; oBox[q * 4 + 1] = (float)bx.y;
                    oBox[q * 4 + 2] = (float)bx.z; oBox[q * 4 + 3] = (float)bx.w;
                    oScore[q] = (float)score64[base + p];
                    oLabel[q] = (float)label[base + p];
                }
            }
        }
    }
}

// ---------------- launch ------------------------------------------------------
extern "C" void kernel_launch(void* const* d_in, const int* in_sizes, int n_in,
                              void* d_out, int out_size, void* d_ws, size_t ws_size,
                              hipStream_t stream) {
    const float* logits = (const float*)d_in[0];
    const float* deltas = (const float*)d_in[1];
    const float* props  = (const float*)d_in[2];
    const int*   imsz   = (const int*)d_in[3];
    char* ws = (char*)d_ws;
    D4*     dbox    = (D4*)(ws + 0);              // 524288
    double* score64 = (double*)(ws + 524288);     // 131072
    int*    label   = (int*)(ws + 655360);        // 65536
    ull*    skeyG   = (ull*)(ws + 720896);        // 131072
    ull*    keptKey = (ull*)(ws + 851968);        // 131072
    float*  out     = (float*)d_out;

    k1_fused<<<dim3(4096), dim3(256), 0, stream>>>(logits, deltas, props, imsz,
                                                   dbox, score64, label, skeyG, keptKey);
    k2_nms<<<dim3(360), dim3(256), 0, stream>>>(dbox, label, skeyG, keptKey);
    k3_top<<<dim3(16), dim3(1024), 0, stream>>>(dbox, score64, label, keptKey, out);
}

// Round 9
// 94.947 us; speedup vs baseline: 1.6901x; 1.0108x over previous
//
#include <hip/hip_runtime.h>
#include <math.h>

#define NN 1024
#define CC 91
#define MAXDET 100
typedef unsigned long long ull;
#define SENT 0xFFFFFFFFFFFFFFFFULL

struct alignas(16) D4 { double x, y, z, w; };

// Branchless f64 exp for x <= 0 (finite or -inf); ~1 ulp; -inf -> 0.0.
// ~20 f64 ops (no OCML call): y=x*log2e; n=rint(y); t=x-n*ln2 (hi/lo);
// exp(t) via 14-FMA Taylor (|t|<=0.347 -> err ~1e-19 rel); scale v_ldexp_f64.
__device__ __forceinline__ double fexp(double x) {
    const double LOG2E = 1.4426950408889634074;
    const double LN2HI = 6.9314718036912381649e-01;
    const double LN2LO = 1.9082149292705877000e-10;
    double y = x * LOG2E;
    double n = rint(y);
    double t = fma(-n, LN2HI, x);
    t = fma(-n, LN2LO, t);
    double p = 1.1470745597729725e-11;          // 1/14!
    p = fma(p, t, 1.6059043836821613e-10);      // 1/13!
    p = fma(p, t, 2.0876756987868099e-09);      // 1/12!
    p = fma(p, t, 2.5052108385441720e-08);      // 1/11!
    p = fma(p, t, 2.7557319223985893e-07);      // 1/10!
    p = fma(p, t, 2.7557319223985890e-06);      // 1/9!
    p = fma(p, t, 2.4801587301587302e-05);      // 1/8!
    p = fma(p, t, 1.9841269841269841e-04);      // 1/7!
    p = fma(p, t, 1.3888888888888889e-03);      // 1/6!
    p = fma(p, t, 8.3333333333333332e-03);      // 1/5!
    p = fma(p, t, 4.1666666666666664e-02);      // 1/4!
    p = fma(p, t, 1.6666666666666666e-01);      // 1/3!
    p = fma(p, t, 0.5);
    p = fma(p, t, 1.0);
    p = fma(p, t, 1.0);
    double r = ldexp(p, (int)n);
    return x < -745.0 ? 0.0 : r;                // covers -inf (NaN path selected away)
}

// ---------------- K1: wave-per-pid softmax + block-level parallel decode ------
// vs round-8 verified version: (a) fmaxf-butterfly + ballot/ctz argmax (same
// smallest-index tie-break; half the dependent shuffle chain), (b) inline fexp
// for the two softmax exps (<=1 ulp vs OCML; sort key drops low 10 mantissa
// bits -> ordering unchanged). Decode tail unchanged (OCML exp, 4 threads).
__global__ __launch_bounds__(256) void k1_fused(
    const float* __restrict__ logits, const float* __restrict__ deltas,
    const float* __restrict__ props,  const int* __restrict__ imsz,
    D4* __restrict__ dbox, double* __restrict__ score64,
    int* __restrict__ label, ull* __restrict__ skeyG, ull* __restrict__ keptKey)
{
    __shared__ double sE[4];
    __shared__ int    sI[4];
    int lane = threadIdx.x & 63;
    int wv   = threadIdx.x >> 6;
    int pid  = blockIdx.x * 4 + wv;            // 0..16383
    const float* lg = logits + (size_t)pid * CC;

    float v0 = lg[lane];
    float v1 = (lane < CC - 64) ? lg[64 + lane] : -INFINITY;

    // max reduce (value only), then argmax via ballot: first matching class 0-63,
    // else first matching class 64-90 -> identical to old smallest-idx tie-break
    float mm = fmaxf(v0, v1);
    #pragma unroll
    for (int off = 32; off > 0; off >>= 1) mm = fmaxf(mm, __shfl_xor(mm, off));
    ull b0 = __ballot(v0 == mm);
    int idx;
    if (b0) idx = __builtin_ctzll(b0);                       // wave-uniform branch
    else    idx = 64 + __builtin_ctzll(__ballot(v1 == mm));

    // fexp(-inf) == 0.0 exactly -> unconditional add matches old exp(-inf) path
    double e = fexp((double)v0 - (double)mm) + fexp((double)v1 - (double)mm);
    #pragma unroll
    for (int off = 32; off > 0; off >>= 1) e += __shfl_xor(e, off);

    if (lane == 0) { sE[wv] = e; sI[wv] = idx; }
    __syncthreads();

    int t = threadIdx.x;
    if (t < 4) {                               // decode the block's 4 pids
        int pid2 = blockIdx.x * 4 + t;
        double score = 1.0 / sE[t];
        int lbl = sI[t];
        int vld = (lbl > 0 && score > 0.05) ? 1 : 0;
        float4 d = ((const float4*)deltas)[(size_t)pid2 * CC + lbl]; // 16B aligned
        float4 p = ((const float4*)props)[pid2];
        double w  = (double)p.z - (double)p.x;
        double h  = (double)p.w - (double)p.y;
        double cx = (double)p.x + 0.5 * w;
        double cy = (double)p.y + 0.5 * h;
        const double CLIPV = 4.135166556742356;  // log(1000/16) in f64
        double dw = fmin((double)d.z, CLIPV), dh = fmin((double)d.w, CLIPV);
        double pcx = (double)d.x * w + cx, pcy = (double)d.y * h + cy;
        double pw = exp(dw) * w, ph = exp(dh) * h;
        double x1 = pcx - 0.5 * pw, y1 = pcy - 0.5 * ph;
        double x2 = pcx + 0.5 * pw, y2 = pcy + 0.5 * ph;
        int b = pid2 >> 10;
        double bw = (double)imsz[b * 2 + 1], bh = (double)imsz[b * 2 + 0];
        x1 = fmin(fmax(x1, 0.0), bw); y1 = fmin(fmax(y1, 0.0), bh);
        x2 = fmin(fmax(x2, 0.0), bw); y2 = fmin(fmax(y2, 0.0), bh);
        dbox[pid2]    = D4{x1, y1, x2, y2};
        score64[pid2] = score;
        label[pid2]   = vld ? lbl : 0;         // 0 = skip in per-class NMS
        // sort key: descending score, ascending orig idx (stable argsort(-s))
        double seff = vld ? score : -1e300;
        ull u   = (ull)__double_as_longlong(seff);
        ull asc = (u >> 63) ? ~u : (u | 0x8000000000000000ULL);
        skeyG[pid2]   = (~asc & ~1023ULL) | (ull)(pid2 & 1023);
        keptKey[pid2] = SENT;
    }
}

// ---------------- K2: one wave per (image,class) greedy NMS -------------------
__global__ __launch_bounds__(256) void k2_nms(
    const D4* __restrict__ dbox, const int* __restrict__ label,
    const ull* __restrict__ skeyG, ull* __restrict__ keptKey)
{
    __shared__ int sMemb[4 * 64];
    __shared__ int sPosR[4 * 64];
    __shared__ ull sKeyR[4 * 64];
    int lane = threadIdx.x & 63, wv = threadIdx.x >> 6;
    int gw = blockIdx.x * 4 + wv;              // 0..1439
    int b  = gw / 90;
    int c  = 1 + gw % 90;                      // classes 1..90
    int base = b * NN;
    ull lmlt = (lane == 0) ? 0ULL : ((1ULL << lane) - 1ULL);

    // hoist: 16 independent coalesced loads -> one exposed latency
    int myl[16];
    #pragma unroll
    for (int w = 0; w < 16; ++w) myl[w] = label[base + w * 64 + lane];

    // ballot-scan members of class c (position order; n>64 impossible, clamp)
    int nmem = 0;
    #pragma unroll
    for (int w = 0; w < 16; ++w) {
        bool match = (myl[w] == c);
        ull mb = __ballot(match);
        if (match) {
            int slot = nmem + (int)__popcll(mb & lmlt);
            if (slot < 64) sMemb[wv * 64 + slot] = w * 64 + lane;
        }
        nmem += (int)__popcll(mb);
        if (nmem >= 64) break;                 // wave-uniform
    }
    int n = nmem < 64 ? nmem : 64;
    if (n == 0) return;                        // no __syncthreads in this kernel

    // rank members by key (score desc, idx asc)
    int p = sMemb[wv * 64 + (lane < n ? lane : 0)];
    ull key = skeyG[base + p];
    int rank = 0;
    for (int j = 0; j < n; ++j) {
        ull kj = __shfl(key, j);
        rank += (int)(kj < key);
    }
    if (lane < n) { sPosR[wv * 64 + rank] = p; sKeyR[wv * 64 + rank] = key; }
    // same-wave DS ops complete in order; compiler inserts lgkmcnt waits
    int rl  = wv * 64 + (lane < n ? lane : 0);
    int p2  = sPosR[rl];
    ull k2v = sKeyR[rl];

    D4 bx = dbox[base + p2];                   // lane r holds rank-r box
    double ma = (bx.z - bx.x) * (bx.w - bx.y);
    ull pm = 0;                                // predecessor-hit mask (rank space)
    for (int j = 0; j < n; ++j) {
        double jx = __shfl(bx.x, j), jy = __shfl(bx.y, j);
        double jz = __shfl(bx.z, j), jw = __shfl(bx.w, j);
        double ja = __shfl(ma, j);
        double xx1 = fmax(bx.x, jx), yy1 = fmax(bx.y, jy);
        double xx2 = fmin(bx.z, jz), yy2 = fmin(bx.w, jw);
        double iw = fmax(xx2 - xx1, 0.0), ih = fmax(yy2 - yy1, 0.0);
        double inter = iw * ih;
        bool hit = (inter > 0.5 * (ma + ja - inter + 1e-9)) && (j < lane);
        pm |= ((ull)hit) << j;
    }
    bool act = lane < n;
    ull avail = __ballot(act);
    ull keptw = 0; bool supp = false;
    while (avail) {
        int k0 = __builtin_ctzll(avail);
        keptw |= 1ULL << k0;
        supp = supp || ((pm >> k0) & 1ULL);
        avail &= ~__ballot(supp);
        avail &= ~((2ULL << k0) - 1ULL);       // k0=63 -> 0
    }
    if (act && ((keptw >> lane) & 1ULL)) keptKey[base + p2] = k2v;
}

// ---------------- K3: per-image top-100 by key via bitonic partial merges -----
__global__ __launch_bounds__(1024) void k3_top(
    const D4* __restrict__ dbox, const double* __restrict__ score64,
    const int* __restrict__ label, const ull* __restrict__ keptKey,
    float* __restrict__ out)
{
    __shared__ ull sRun[NN];
    int b = blockIdx.x, t = threadIdx.x;
    int lane = t & 63, wv = t >> 6;
    int base = b * NN;

    // in-wave 64-element bitonic sort, ascending (key asc == score desc)
    ull key = keptKey[base + t];
    for (int k = 2; k <= 64; k <<= 1)
        for (int j = k >> 1; j > 0; j >>= 1) {
            ull part = __shfl_xor(key, j);
            bool keepMin = ((lane & j) == 0) == ((lane & k) == 0);
            ull mn = key < part ? key : part;
            ull mx = key < part ? part : key;
            key = keepMin ? mn : mx;
        }
    sRun[wv * 64 + lane] = key;
    __syncthreads();

    // L1: merge pairs of sorted-64 -> sorted-128 (waves 0..7)
    if (wv < 8) {
        ull a  = sRun[wv * 128 + lane];
        ull bb = sRun[wv * 128 + 64 + lane];
        ull br = __shfl(bb, 63 - lane);
        ull lo = a < br ? a : br;
        ull hi = a < br ? br : a;
        #pragma unroll
        for (int j = 32; j > 0; j >>= 1) {
            bool km = ((lane & j) == 0);
            ull pl = __shfl_xor(lo, j);
            lo = km ? (lo < pl ? lo : pl) : (lo < pl ? pl : lo);
            ull ph = __shfl_xor(hi, j);
            hi = km ? (hi < ph ? hi : ph) : (hi < ph ? ph : hi);
        }
        sRun[wv * 128 + lane] = lo;
        sRun[wv * 128 + 64 + lane] = hi;
    }
    // L2..L4: truncated merges of sorted-128 pairs -> smallest-128 sorted
    for (int nm = 4; nm >= 1; nm >>= 1) {
        __syncthreads();
        ull Alo = 0, Ahi = 0, Blo = 0, Bhi = 0;
        if (wv < nm) {
            Alo = sRun[wv * 256 + lane];
            Ahi = sRun[wv * 256 + 64 + lane];
            Blo = sRun[wv * 256 + 128 + lane];
            Bhi = sRun[wv * 256 + 192 + lane];
        }
        __syncthreads();
        if (wv < nm) {
            ull rBhi = __shfl(Bhi, 63 - lane);
            ull rBlo = __shfl(Blo, 63 - lane);
            ull Mlo = Alo < rBhi ? Alo : rBhi;   // min(A[i], B[127-i]) -> bitonic,
            ull Mhi = Ahi < rBlo ? Ahi : rBlo;   // contains the 128 smallest
            ull l2 = Mlo < Mhi ? Mlo : Mhi;      // clean stage j=64
            ull h2 = Mlo < Mhi ? Mhi : Mlo;
            #pragma unroll
            for (int j = 32; j > 0; j >>= 1) {
                bool km = ((lane & j) == 0);
                ull pl = __shfl_xor(l2, j);
                l2 = km ? (l2 < pl ? l2 : pl) : (l2 < pl ? pl : l2);
                ull ph = __shfl_xor(h2, j);
                h2 = km ? (h2 < ph ? h2 : ph) : (h2 < ph ? ph : h2);
            }
            sRun[wv * 128 + lane] = l2;
            sRun[wv * 128 + 64 + lane] = h2;
        }
    }
    // wave 0 wrote final sorted-128 to sRun[0..127]; same-wave read is ordered
    if (wv == 0) {
        float* oBox   = out;
        float* oScore = out + 6400;
        float* oLabel = out + 8000;
        #pragma unroll
        for (int rsel = 0; rsel < 2; ++rsel) {
            int rank = rsel * 64 + lane;
            if (rank < MAXDET) {
                ull kf = sRun[rsel * 64 + lane];
                int q = b * MAXDET + rank;
                if (kf == SENT) {
                    oBox[q * 4 + 0] = 0.f; oBox[q * 4 + 1] = 0.f;
                    oBox[q * 4 + 2] = 0.f; oBox[q * 4 + 3] = 0.f;
                    oScore[q] = 0.f;
                    oLabel[q] = -1.f;
                } else {
                    int p = (int)(kf & 1023ULL);
                    D4 bx = dbox[base + p];
                    oBox[q * 4 + 0] = (float)bx.x; oBox[q * 4 + 1] = (float)bx.y;
                    oBox[q * 4 + 2] = (float)bx.z; oBox[q * 4 + 3] = (float)bx.w;
                    oScore[q] = (float)score64[base + p];
                    oLabel[q] = (float)label[base + p];
                }
            }
        }
    }
}

// ---------------- launch ------------------------------------------------------
extern "C" void kernel_launch(void* const* d_in, const int* in_sizes, int n_in,
                              void* d_out, int out_size, void* d_ws, size_t ws_size,
                              hipStream_t stream) {
    const float* logits = (const float*)d_in[0];
    const float* deltas = (const float*)d_in[1];
    const float* props  = (const float*)d_in[2];
    const int*   imsz   = (const int*)d_in[3];
    char* ws = (char*)d_ws;
    D4*     dbox    = (D4*)(ws + 0);              // 524288
    double* score64 = (double*)(ws + 524288);     // 131072
    int*    label   = (int*)(ws + 655360);        // 65536
    ull*    skeyG   = (ull*)(ws + 720896);        // 131072
    ull*    keptKey = (ull*)(ws + 851968);        // 131072
    float*  out     = (float*)d_out;

    k1_fused<<<dim3(4096), dim3(256), 0, stream>>>(logits, deltas, props, imsz,
                                                   dbox, score64, label, skeyG, keptKey);
    k2_nms<<<dim3(360), dim3(256), 0, stream>>>(dbox, label, skeyG, keptKey);
    k3_top<<<dim3(16), dim3(1024), 0, stream>>>(dbox, score64, label, keptKey, out);
}